// Round 4
// baseline (41.863 us; speedup 1.0000x reference)
//
#include <hip/hip_runtime.h>

#define D_IN  48
#define H_IN  64
#define W_IN  128
#define D_OUT 193
#define H_OUT 256
#define W_OUT 512
#define NCOL  34    // staged cols: 32 distinct w0 + 1 left-guard + 1 pair-neighbor

// 2 threads per output pixel, wave-uniform split of the d-range:
//   threads   0..127: half 0 -> d in [0,95],   needs c[k], k in [0,24]
//   threads 128..255: half 1 -> d in [96,192], needs c[k], k in [23,47]
// Doubles wave count (8 waves/SIMD) and halves per-thread register state
// (c[25]); __launch_bounds__(256,8) pins VGPR<=64 so 8 waves are resident.
//
// Softmax args within one k-segment are arithmetic in d -> exp values form a
// geometric progression: 2 exps + len-1 muls per segment (~100 exps/pixel
// instead of 193). Halves merged with a shifted-softmax combine via LDS.
__global__ __launch_bounds__(256, 8) void disp_kernel(const float* __restrict__ x,
                                                      float* __restrict__ out);

template<int HV>
__device__ __forceinline__ void compute_half(const float* base,
                                             float w00, float w01, float w10, float w11,
                                             float& m_out, float& s_out, float& ds_out) {
    constexpr int K0  = HV ? 23 : 0;
    constexpr int KLO = HV ? 23 : 0;
    constexpr int KHI = HV ? 46 : 23;
    constexpr int DMIN = HV ? 96 : 2;     // main-range d (clamped ends handled apart)
    constexpr int DMAX = HV ? 190 : 95;

    // bilinear column slice c[j] = c_global[K0+j], track local min
    float c[25];
    float cmin = 1e30f;
    #pragma unroll
    for (int j = 0; j < 25; ++j) {
        const float* p = base + (2 * (K0 + j)) * NCOL;
        float a0 = p[0], a1 = p[1], b0 = p[NCOL], b1 = p[NCOL + 1];
        float v = w00 * a0 + w01 * a1 + w10 * b0 + w11 * b1;
        c[j] = v;
        cmin = fminf(cmin, v);
    }

    // g[j] = (cmin - c[j]) * log2e   (<= 0), in place
    const float L2E = 1.4426950408889634f;
    float gb = cmin * L2E;
    #pragma unroll
    for (int j = 0; j < 25; ++j) c[j] = fmaf(c[j], -L2E, gb);

    float s0 = 0.f, s1 = 0.f, ds0 = 0.f, ds1 = 0.f;

    if (HV == 0) {            // d=0,1: fd clamps to 0 -> arg = g[0]
        float e0;
        asm("v_exp_f32 %0, %1" : "=v"(e0) : "v"(c[0]));
        s0 = e0 + e0;         // d=0 and d=1
        ds0 = e0;             // 0*e + 1*e
    }

    // main segments: df(d) = (96d-145)/386; segment k covers
    // d in [ceil((386k+145)/96), ceil((386(k+1)+145)/96)-1]
    #pragma unroll
    for (int k = KLO; k <= KHI; ++k) {
        int dlo = (386 * k + 145 + 95) / 96;       if (dlo < DMIN) dlo = DMIN;
        int dhi = (386 * (k + 1) + 145 + 95) / 96 - 1; if (dhi > DMAX) dhi = DMAX;
        int j0 = k - K0;
        float delta = c[j0 + 1] - c[j0];
        float f0 = (float)(96 * dlo - 145 - 386 * k) * (1.0f / 386.0f);
        float arg0 = fmaf(f0, delta, c[j0]);
        float e, r;
        asm("v_exp_f32 %0, %1" : "=v"(e) : "v"(arg0));
        float rarg = delta * (96.0f / 386.0f);
        asm("v_exp_f32 %0, %1" : "=v"(r) : "v"(rarg));
        #pragma unroll
        for (int u = 0; u < 5; ++u) {              // max segment length 5
            int d = dlo + u;
            if (d <= dhi) {
                if (d & 1) { s1 += e; ds1 = fmaf((float)d, e, ds1); }
                else       { s0 += e; ds0 = fmaf((float)d, e, ds0); }
                e *= r;
            }
        }
    }

    if (HV == 1) {            // d=191,192: k0 clamps to 47, fd=0 -> arg = g[47]
        float e;
        asm("v_exp_f32 %0, %1" : "=v"(e) : "v"(c[24]));
        s0 += e + e;
        ds0 = fmaf(383.f, e, ds0);   // 191*e + 192*e
    }

    m_out  = cmin;
    s_out  = (s0 + s1);
    ds_out = (ds0 + ds1);
}

__global__ __launch_bounds__(256, 8) void disp_kernel(const float* __restrict__ x,
                                                      float* __restrict__ out) {
    __shared__ float sm[D_IN * 2 * NCOL];    // 13056 B
    __shared__ float red_m[256], red_s[256], red_d[256];   // 3 KB merge buffers

    int t = threadIdx.x;
    int p0 = blockIdx.x << 7;                // first pixel of block
    int p = p0 + (t & 127);
    int w = p & (W_OUT - 1);
    int h = (p >> 9) & (H_OUT - 1);          // uniform within block
    int b = p >> 17;                          // uniform
    int wblk = p0 & (W_OUT - 1);

    // --- h interpolation (uniform; half-pixel, clamp as pair+frac) ---
    float hf = (h + 0.5f) * 0.25f - 0.5f;
    float hfl = floorf(hf);
    int h0 = (int)hfl;
    float fh = hf - hfl;
    int hp; float fhp;
    if (h0 < 0)              { hp = 0;        fhp = 0.f; }
    else if (h0 >= H_IN - 1) { hp = H_IN - 2; fhp = 1.f; }
    else                     { hp = h0;       fhp = fh;  }

    // --- w interpolation ---
    float wf = (w + 0.5f) * 0.25f - 0.5f;
    float wfl = floorf(wf);
    int w0 = (int)wfl;
    float fw = wf - wfl;
    int wp; float fwp;
    if (w0 < 0)              { wp = 0;        fwp = 0.f; }
    else if (w0 >= W_IN - 1) { wp = W_IN - 2; fwp = 1.f; }
    else                     { wp = w0;       fwp = fw;  }

    // --- cooperative staging: sm[k][r][j] = x[b][k][hp+r][clamp(col0+j)] ---
    int col0 = (wblk >> 2) - 1; if (col0 < 0) col0 = 0;
    const float* xrow = x + (size_t)b * (D_IN * H_IN * W_IN) + hp * W_IN;
    for (int i = t; i < D_IN * 2 * NCOL; i += 256) {
        int k   = i / (2 * NCOL);
        int rem = i - k * (2 * NCOL);
        int r   = rem / NCOL;
        int j   = rem - r * NCOL;
        int col = col0 + j; if (col > W_IN - 1) col = W_IN - 1;
        sm[i] = xrow[k * (H_IN * W_IN) + r * W_IN + col];
    }
    __syncthreads();

    float w00 = (1.f - fhp) * (1.f - fwp);
    float w01 = (1.f - fhp) * fwp;
    float w10 = fhp * (1.f - fwp);
    float w11 = fhp * fwp;

    const float* base = &sm[wp - col0];
    float m, S, D;
    if (t < 128) compute_half<0>(base, w00, w01, w10, w11, m, S, D);
    else         compute_half<1>(base, w00, w01, w10, w11, m, S, D);

    red_m[t] = m; red_s[t] = S; red_d[t] = D;
    __syncthreads();

    if (t < 128) {
        float mA = red_m[t],      sA = red_s[t],      dA = red_d[t];
        float mB = red_m[t + 128], sB = red_s[t + 128], dB = red_d[t + 128];
        const float L2E = 1.4426950408889634f;
        float mu = fminf(mA, mB);
        float fA, fB;
        float aA = (mu - mA) * L2E;
        float aB = (mu - mB) * L2E;
        asm("v_exp_f32 %0, %1" : "=v"(fA) : "v"(aA));
        asm("v_exp_f32 %0, %1" : "=v"(fB) : "v"(aB));
        out[p] = (dA * fA + dB * fB) / (sA * fA + sB * fB);
    }
}

extern "C" void kernel_launch(void* const* d_in, const int* in_sizes, int n_in,
                              void* d_out, int out_size, void* d_ws, size_t ws_size,
                              hipStream_t stream) {
    const float* x = (const float*)d_in[0];
    float* out = (float*)d_out;
    int total_pixels = 2 * H_OUT * W_OUT;      // 262144
    int blocks = total_pixels / 128;           // 2048 (2 threads/pixel)
    disp_kernel<<<blocks, 256, 0, stream>>>(x, out);
}

// Round 5
// 16.689 us; speedup vs baseline: 2.5084x; 2.5084x over previous
//
#include <hip/hip_runtime.h>

#define D_IN  48
#define H_IN  64
#define W_IN  128
#define D_OUT 193
#define H_OUT 256
#define W_OUT 512
#define NCOL  34    // staged cols: 32 distinct w0 + 1 left-guard + 1 pair-neighbor

// 2 threads per output pixel, wave-uniform split of the d-range:
//   threads   0..127: half 0 -> d in [0,95],   needs c[k], k in [0,24]
//   threads 128..255: half 1 -> d in [96,192], needs c[k], k in [23,47]
// 2048 blocks x 4 waves = 8192 waves = full 256CUx32 wave capacity, provided
// VGPR <= 64. NO forced min-waves: R3's __launch_bounds__(256,8) capped VGPR
// at 32 -> 139 MB of scratch spill traffic (FETCH 53.6MB/WRITE 85MB) = the
// entire 51us. Let the allocator pick (~50-60 VGPR for c[25]+temps).
//
// h is block-uniform -> fold the h-lerp into LDS staging: sm[k][j] is already
// h-interpolated, so per-k bilinear = one adjacent-pair LDS read + sub + fma.
//
// Softmax args within one k-segment are arithmetic in d -> exp values form a
// geometric progression: 2 exps + (len-1) muls per segment (~50 exps/thread).
// Halves merged with a shifted-softmax combine via LDS.

template<int HV>
__device__ __forceinline__ void compute_half(const float* base, float fwp,
                                             float& m_out, float& s_out, float& ds_out) {
    constexpr int K0   = HV ? 23 : 0;
    constexpr int KLO  = HV ? 23 : 0;
    constexpr int KHI  = HV ? 46 : 23;
    constexpr int DMIN = HV ? 96 : 2;     // main-range d (clamped ends handled apart)
    constexpr int DMAX = HV ? 190 : 95;

    // w-lerp column slice c[j] = c_global[K0+j] from h-prelerped LDS rows
    float c[25];
    float cmin = 1e30f;
    #pragma unroll
    for (int j = 0; j < 25; ++j) {
        const float* p = base + (K0 + j) * NCOL;
        float a = p[0], b = p[1];
        float v = fmaf(fwp, b - a, a);
        c[j] = v;
        cmin = fminf(cmin, v);
    }

    // g[j] = (cmin - c[j]) * log2e   (<= 0), in place
    const float L2E = 1.4426950408889634f;
    float gb = cmin * L2E;
    #pragma unroll
    for (int j = 0; j < 25; ++j) c[j] = fmaf(c[j], -L2E, gb);

    float s0 = 0.f, s1 = 0.f, ds0 = 0.f, ds1 = 0.f;

    if (HV == 0) {            // d=0,1: fd clamps to 0 -> arg = g[0]
        float e0;
        asm("v_exp_f32 %0, %1" : "=v"(e0) : "v"(c[0]));
        s0 = e0 + e0;         // d=0 and d=1
        ds0 = e0;             // 0*e + 1*e
    }

    // main segments: df(d) = (96d-145)/386; segment k covers
    // d in [ceil((386k+145)/96), ceil((386(k+1)+145)/96)-1]
    #pragma unroll
    for (int k = KLO; k <= KHI; ++k) {
        int dlo = (386 * k + 145 + 95) / 96;           if (dlo < DMIN) dlo = DMIN;
        int dhi = (386 * (k + 1) + 145 + 95) / 96 - 1; if (dhi > DMAX) dhi = DMAX;
        int j0 = k - K0;
        float delta = c[j0 + 1] - c[j0];
        float f0 = (float)(96 * dlo - 145 - 386 * k) * (1.0f / 386.0f);  // literal
        float arg0 = fmaf(f0, delta, c[j0]);
        float e, r;
        asm("v_exp_f32 %0, %1" : "=v"(e) : "v"(arg0));
        float rarg = delta * (96.0f / 386.0f);
        asm("v_exp_f32 %0, %1" : "=v"(r) : "v"(rarg));
        #pragma unroll
        for (int u = 0; u < 5; ++u) {                  // max segment length 5
            int d = dlo + u;
            if (d <= dhi) {
                if (d & 1) { s1 += e; ds1 = fmaf((float)d, e, ds1); }
                else       { s0 += e; ds0 = fmaf((float)d, e, ds0); }
                e *= r;
            }
        }
    }

    if (HV == 1) {            // d=191,192: k0 clamps to 47, fd=0 -> arg = g[47]
        float e;
        asm("v_exp_f32 %0, %1" : "=v"(e) : "v"(c[24]));
        s0 += e + e;
        ds0 = fmaf(383.f, e, ds0);   // 191*e + 192*e
    }

    m_out  = cmin;
    s_out  = (s0 + s1);
    ds_out = (ds0 + ds1);
}

__global__ __launch_bounds__(256) void disp_kernel(const float* __restrict__ x,
                                                   float* __restrict__ out) {
    __shared__ float sm[D_IN * NCOL];                      // 6528 B, h-prelerped
    __shared__ float red_m[256], red_s[256], red_d[256];   // 3 KB merge buffers

    int t = threadIdx.x;
    int p0 = blockIdx.x << 7;                // first pixel of block
    int p = p0 + (t & 127);
    int w = p & (W_OUT - 1);
    int h = (p >> 9) & (H_OUT - 1);          // uniform within block
    int b = p >> 17;                          // uniform
    int wblk = p0 & (W_OUT - 1);

    // --- h interpolation (uniform; half-pixel, clamp as pair+frac) ---
    float hf = (h + 0.5f) * 0.25f - 0.5f;
    float hfl = floorf(hf);
    int h0 = (int)hfl;
    float fh = hf - hfl;
    int hp; float fhp;
    if (h0 < 0)              { hp = 0;        fhp = 0.f; }
    else if (h0 >= H_IN - 1) { hp = H_IN - 2; fhp = 1.f; }
    else                     { hp = h0;       fhp = fh;  }

    // --- w interpolation ---
    float wf = (w + 0.5f) * 0.25f - 0.5f;
    float wfl = floorf(wf);
    int w0 = (int)wfl;
    float fw = wf - wfl;
    int wp; float fwp;
    if (w0 < 0)              { wp = 0;        fwp = 0.f; }
    else if (w0 >= W_IN - 1) { wp = W_IN - 2; fwp = 1.f; }
    else                     { wp = w0;       fwp = fw;  }

    // --- cooperative staging with fused h-lerp:
    //     sm[k][j] = lerp(x[b][k][hp][col], x[b][k][hp+1][col], fhp) ---
    int col0 = (wblk >> 2) - 1; if (col0 < 0) col0 = 0;
    const float* xrow = x + (size_t)b * (D_IN * H_IN * W_IN) + hp * W_IN;
    for (int i = t; i < D_IN * NCOL; i += 256) {
        int k = i / NCOL;
        int j = i - k * NCOL;
        int col = col0 + j; if (col > W_IN - 1) col = W_IN - 1;
        const float* q = xrow + k * (H_IN * W_IN) + col;
        float a = q[0], bq = q[W_IN];
        sm[i] = fmaf(fhp, bq - a, a);
    }
    __syncthreads();

    const float* base = &sm[wp - col0];
    float m, S, D;
    if (t < 128) compute_half<0>(base, fwp, m, S, D);
    else         compute_half<1>(base, fwp, m, S, D);

    red_m[t] = m; red_s[t] = S; red_d[t] = D;
    __syncthreads();

    if (t < 128) {
        float mA = red_m[t],       sA = red_s[t],       dA = red_d[t];
        float mB = red_m[t + 128], sB = red_s[t + 128], dB = red_d[t + 128];
        const float L2E = 1.4426950408889634f;
        float mu = fminf(mA, mB);
        float fA, fB;
        float aA = (mu - mA) * L2E;
        float aB = (mu - mB) * L2E;
        asm("v_exp_f32 %0, %1" : "=v"(fA) : "v"(aA));
        asm("v_exp_f32 %0, %1" : "=v"(fB) : "v"(aB));
        out[p] = (dA * fA + dB * fB) / (sA * fA + sB * fB);
    }
}

extern "C" void kernel_launch(void* const* d_in, const int* in_sizes, int n_in,
                              void* d_out, int out_size, void* d_ws, size_t ws_size,
                              hipStream_t stream) {
    const float* x = (const float*)d_in[0];
    float* out = (float*)d_out;
    int total_pixels = 2 * H_OUT * W_OUT;      // 262144
    int blocks = total_pixels / 128;           // 2048 (2 threads/pixel)
    disp_kernel<<<blocks, 256, 0, stream>>>(x, out);
}